// Round 8
// baseline (402.351 us; speedup 1.0000x reference)
//
#include <hip/hip_runtime.h>
#include <hip/hip_cooperative_groups.h>

namespace cg = cooperative_groups;

#define KH_   10
#define KW_   4
#define W_    64
#define K1_   5120       // C*KH*KW
#define WK_   61
#define JP_   5824       // 91*64
#define NZ    819200
#define KS1   8          // k-split gemm1 (chunk 640, 20 iters of 32)
#define KS2   8          // jp-split gemm2
#define GRIDC 256        // coop grid: 1 block/CU guaranteed co-resident

typedef __attribute__((ext_vector_type(8))) short short8;
typedef __attribute__((ext_vector_type(4))) short short4v;
typedef __attribute__((ext_vector_type(4))) float f32x4;

__device__ __forceinline__ unsigned short f2bf(float f) {
    unsigned int u = __float_as_uint(f);
    return (unsigned short)((u + 0x8000u) >> 16);
}

// ===========================================================================
// Phase bodies — identical logic to the R6 proven kernels.
// ===========================================================================

__device__ __forceinline__ void pack_body(int tid,
                                          const float* __restrict__ z1,
                                          const float* __restrict__ z2,
                                          unsigned short* __restrict__ Qb2,
                                          unsigned short* __restrict__ Z2s,
                                          unsigned short* __restrict__ X) {
    if (tid < 102400) {                       // Qb2 octs (frag layout)
        int ko = tid / 160, i = tid - ko * 160;
        int d0 = ko * 8;
        int c = d0 / 40, rr = d0 - c * 40;
        int kh0 = rr >> 2;                    // even
        int ih = i >> 4, iw = i & 15;
        int a0 = c * 6400 + (ih * KH_ + kh0) * W_ + iw * KW_;
        unsigned short v[8];
#pragma unroll
        for (int s = 0; s < 4; ++s) v[s] = f2bf(z1[a0 + s]);
#pragma unroll
        for (int s = 0; s < 4; ++s) v[4 + s] = f2bf(z1[a0 + W_ + s]);
        *(short8*)(Qb2 + (size_t)tid * 8) = *(short8*)v;
    } else if (tid < 512000) {                // Z2s octs
        int o = tid - 102400;
        int kw = o / 102400, r8 = o - kw * 102400;
        int e0 = r8 * 8;
        int w0 = e0 & 63, rowbase = e0 - w0;
        unsigned short v[8];
#pragma unroll
        for (int s = 0; s < 8; ++s) v[s] = f2bf(z2[rowbase + min(w0 + s + kw, 63)]);
        *(short8*)(Z2s + (size_t)kw * NZ + e0) = *(short8*)v;
    } else {                                  // X octs
        int o = tid - 512000;                 // o = (c*100+h)*64 + w
        int w = o & 63, ch = o >> 6;
        int h = ch % 100;
        int ch2 = (h < 99) ? ch + 1 : ch;
        unsigned short v[8];
#pragma unroll
        for (int s = 0; s < 4; ++s) v[s] = f2bf(z2[ch * 64 + min(w + s, 63)]);
#pragma unroll
        for (int s = 0; s < 4; ++s) v[4 + s] = f2bf(z2[ch2 * 64 + min(w + s, 63)]);
        *(short8*)(X + (size_t)o * 8) = *(short8*)v;
    }
}

__device__ __forceinline__ void gemm1_body(int vb, int t,
                                           const unsigned short* __restrict__ Qb2,
                                           const unsigned short* __restrict__ X,
                                           float* __restrict__ Sp) {
    const int ksp = vb & 7;              // 0..7
    const int hkt = vb >> 3;             // 0..45
    const int hk0 = hkt * 2;
    const int wave = t >> 6, lane = t & 63;
    const int mh = wave & 1, nh = wave >> 1;   // wave tile 80 x 64
    const int l15 = lane & 15, q = lane >> 4;

    int band[4], wk[4];
#pragma unroll
    for (int n = 0; n < 4; ++n) {
        int jpn = (nh * 4 + n) * 16 + l15;
        band[n] = jpn >> 6;
        wk[n]   = jpn & 63;
    }
    int rowA[5];
#pragma unroll
    for (int b = 0; b < 5; ++b) rowA[b] = (mh * 5 + b) * 16 + l15;

    f32x4 acc[5][4];
#pragma unroll
    for (int b = 0; b < 5; ++b)
#pragma unroll
        for (int n = 0; n < 4; ++n) acc[b][n] = (f32x4){0.f, 0.f, 0.f, 0.f};

    for (int it = 0; it < 20; ++it) {
        const unsigned short* Ab = Qb2 + ((size_t)(ksp * 80 + it * 4 + q) * 160) * 8;
        short8 af[5], bf[4];
#pragma unroll
        for (int b = 0; b < 5; ++b)
            af[b] = *(const short8*)(Ab + rowA[b] * 8);
        int d0 = ksp * 640 + it * 32 + q * 8;
        unsigned du = (unsigned)d0;
        int c = du / 40u, rr = d0 - c * 40;
        int kh0 = rr >> 2;               // even
        const unsigned short* Bb = X + ((size_t)(c * 100 + hk0 + kh0) * 64) * 8;
#pragma unroll
        for (int n = 0; n < 4; ++n)
            bf[n] = *(const short8*)(Bb + (band[n] * 64 + wk[n]) * 8);
#pragma unroll
        for (int b = 0; b < 5; ++b)
#pragma unroll
            for (int n = 0; n < 4; ++n)
                acc[b][n] = __builtin_amdgcn_mfma_f32_16x16x32_bf16(af[b], bf[n], acc[b][n], 0, 0, 0);
    }
    float* base = Sp + (size_t)ksp * (160 * JP_);
#pragma unroll
    for (int b = 0; b < 5; ++b) {
        int i0 = (mh * 5 + b) * 16 + q * 4;
#pragma unroll
        for (int n = 0; n < 4; ++n) {
            int jg = hkt * 128 + (nh * 4 + n) * 16 + l15;
            if (jg < JP_) {
#pragma unroll
                for (int r = 0; r < 4; ++r)
                    base[(size_t)(i0 + r) * JP_ + jg] = acc[b][n][r];
            }
        }
    }
}

__device__ __forceinline__ void softmax_body(int i, int t,
                                             const float* __restrict__ Sp,
                                             unsigned short* __restrict__ Atn2) {
    const int wave = t >> 6, lane = t & 63;
    __shared__ float red2[4];
    f32x4 v[6];
    float s = 0.f;
#pragma unroll
    for (int jj = 0; jj < 6; ++jj) {
        int q4 = t + jj * 256;
        f32x4 r = (f32x4){0.f, 0.f, 0.f, 0.f};
        if (q4 < 1456) {
            f32x4 a = (f32x4){0.f, 0.f, 0.f, 0.f};
#pragma unroll
            for (int p = 0; p < KS1; ++p)
                a += *(const f32x4*)(Sp + (size_t)p * (160 * JP_) + (size_t)i * JP_ + q4 * 4);
            a *= (1.0f / 5120.0f);
            bool pad_hi = (((q4 * 4) & 63) == 60);  // cols 61,62,63 of a band
#pragma unroll
            for (int e = 0; e < 4; ++e) {
                bool ok = !(pad_hi && e > 0);
                float x = ok ? __expf(a[e]) : 0.f;
                r[e] = x;
                s += x;
            }
        }
        v[jj] = r;
    }
#pragma unroll
    for (int off = 32; off >= 1; off >>= 1) s += __shfl_xor(s, off);
    if (lane == 0) red2[wave] = s;
    __syncthreads();
    float inv = 1.0f / (red2[0] + red2[1] + red2[2] + red2[3]);
#pragma unroll
    for (int jj = 0; jj < 6; ++jj) {
        int q4 = t + jj * 256;
        if (q4 < 1456) {
            short4v u;
            u.x = (short)f2bf(v[jj].x * inv);
            u.y = (short)f2bf(v[jj].y * inv);
            u.z = (short)f2bf(v[jj].z * inv);
            u.w = (short)f2bf(v[jj].w * inv);
            *(short4v*)(Atn2 + ((size_t)(q4 >> 1) * 160 + i) * 8 + (q4 & 1) * 4) = u;
        }
    }
}

__device__ __forceinline__ void gemm2_body(int vb, int t,
                                           const unsigned short* __restrict__ Atn2,
                                           const unsigned short* __restrict__ Z2s,
                                           float* __restrict__ Op) {
    __shared__ short As[128 * 40];   // KV^T tile [d_local][jp_local], stride 40 (2-way, free)
    const int ksp = vb & 7;              // 0..7
    const int dt = vb >> 3;              // 0..39
    const int dbase = dt * 128;
    const int it0 = (182 * ksp) >> 3;
    const int it1 = (182 * (ksp + 1)) >> 3;
    const int wave = t >> 6, lane = t & 63;
    const int mh = wave & 1, nh = wave >> 1;   // wave tile 64(d) x 80(i)
    const int l15 = lane & 15, q = lane >> 4;

    const int dl_s = t >> 2, jg_s = t & 3;
    f32x4 acc[4][5];
#pragma unroll
    for (int m = 0; m < 4; ++m)
#pragma unroll
        for (int n = 0; n < 5; ++n) acc[m][n] = (f32x4){0.f, 0.f, 0.f, 0.f};

    for (int it = it0; it < it1; ++it) {
        int k0 = it * 32;
        __syncthreads();                 // also covers As WAR across vb iterations
#pragma unroll
        for (int s = 0; s < 2; ++s) {
            int dl = dl_s + s * 64, jg = jg_s;
            int d = dbase + dl;
            unsigned du = (unsigned)d;
            int c = du / 40u, rr = d - c * 40;
            int kh = rr >> 2, kw = rr & 3;
            int jp0 = k0 + jg * 8;
            int hk = jp0 >> 6, wk0 = jp0 & 63;
            int src = kw * NZ + c * 6400 + (hk + kh) * W_ + wk0;
            *(short8*)&As[dl * 40 + jg * 8] = *(const short8*)(Z2s + src);
        }
        __syncthreads();
        short8 af[4], bf[5];
#pragma unroll
        for (int m = 0; m < 4; ++m)
            af[m] = *(const short8*)&As[(mh * 64 + m * 16 + l15) * 40 + q * 8];
        const unsigned short* Bb = Atn2 + ((size_t)((k0 >> 3) + q) * 160) * 8;
#pragma unroll
        for (int n = 0; n < 5; ++n)
            bf[n] = *(const short8*)(Bb + ((nh * 5 + n) * 16 + l15) * 8);
#pragma unroll
        for (int m = 0; m < 4; ++m)
#pragma unroll
            for (int n = 0; n < 5; ++n)
                acc[m][n] = __builtin_amdgcn_mfma_f32_16x16x32_bf16(af[m], bf[n], acc[m][n], 0, 0, 0);
    }
    float* base = Op + (size_t)ksp * ((size_t)NZ);
#pragma unroll
    for (int m = 0; m < 4; ++m) {
        int d0 = dbase + mh * 64 + m * 16 + q * 4;
#pragma unroll
        for (int n = 0; n < 5; ++n) {
            int i = (nh * 5 + n) * 16 + l15;
#pragma unroll
            for (int r = 0; r < 4; ++r)
                base[(size_t)(d0 + r) * 160 + i] = acc[m][n][r];
        }
    }
}

__device__ __forceinline__ void reduce_body(int tid,
                                            const float* __restrict__ Op,
                                            float* __restrict__ out) {
    int f = tid * 4;
    f32x4 s = (f32x4){0.f, 0.f, 0.f, 0.f};
#pragma unroll
    for (int p = 0; p < KS2; ++p) s += *(const f32x4*)(Op + (size_t)p * NZ + f);
    int d = f / 160, i0 = f - d * 160;    // x4 block never straddles d
    int c = d / 40, rr = d - c * 40;
    int kh = rr >> 2, kw = rr & 3;
#pragma unroll
    for (int r = 0; r < 4; ++r) {
        int i = i0 + r;
        int ih = i >> 4, iw = i & 15;
        out[c * 6400 + (ih * KH_ + kh) * W_ + iw * KW_ + kw] = s[r];
    }
}

// ===========================================================================
// Cooperative fused kernel (grid GRIDC=256 -> 1 block/CU, always co-resident)
// ===========================================================================
__global__ __launch_bounds__(256) void fused_kernel(const float* __restrict__ z1,
                                                    const float* __restrict__ z2,
                                                    unsigned short* __restrict__ Qb2,
                                                    unsigned short* __restrict__ Z2s,
                                                    unsigned short* __restrict__ X,
                                                    unsigned short* __restrict__ Atn2,
                                                    float* __restrict__ Sp,
                                                    float* __restrict__ Op,
                                                    float* __restrict__ out) {
    cg::grid_group grid = cg::this_grid();
    const int bid = blockIdx.x, t = threadIdx.x;

    for (int tid = bid * 256 + t; tid < 1331200; tid += GRIDC * 256)
        pack_body(tid, z1, z2, Qb2, Z2s, X);
    __threadfence();
    grid.sync();

    for (int vb = bid; vb < 368; vb += GRIDC)
        gemm1_body(vb, t, Qb2, X, Sp);
    __threadfence();
    grid.sync();

    for (int vb = bid; vb < 160; vb += GRIDC)
        softmax_body(vb, t, Sp, Atn2);
    __threadfence();
    grid.sync();

    for (int vb = bid; vb < 320; vb += GRIDC)
        gemm2_body(vb, t, Atn2, Z2s, Op);
    __threadfence();
    grid.sync();

    for (int tid = bid * 256 + t; tid < 204800; tid += GRIDC * 256)
        reduce_body(tid, Op, out);
}

// ===========================================================================
// Fallback wrappers (R6 configuration — proven 139 us)
// ===========================================================================
__global__ __launch_bounds__(256) void pack_kernel(const float* __restrict__ z1,
                                                   const float* __restrict__ z2,
                                                   unsigned short* __restrict__ Qb2,
                                                   unsigned short* __restrict__ Z2s,
                                                   unsigned short* __restrict__ X) {
    int tid = blockIdx.x * 256 + threadIdx.x;
    if (tid < 1331200) pack_body(tid, z1, z2, Qb2, Z2s, X);
}
__global__ __launch_bounds__(256) void gemm1_kernel(const unsigned short* __restrict__ Qb2,
                                                    const unsigned short* __restrict__ X,
                                                    float* __restrict__ Sp) {
    gemm1_body(blockIdx.x, threadIdx.x, Qb2, X, Sp);
}
__global__ __launch_bounds__(256) void softmax_kernel(const float* __restrict__ Sp,
                                                      unsigned short* __restrict__ Atn2) {
    softmax_body(blockIdx.x, threadIdx.x, Sp, Atn2);
}
__global__ __launch_bounds__(256) void gemm2_kernel(const unsigned short* __restrict__ Atn2,
                                                    const unsigned short* __restrict__ Z2s,
                                                    float* __restrict__ Op) {
    gemm2_body(blockIdx.x, threadIdx.x, Atn2, Z2s, Op);
}
__global__ __launch_bounds__(256) void reduce_kernel(const float* __restrict__ Op,
                                                     float* __restrict__ out) {
    reduce_body(blockIdx.x * 256 + threadIdx.x, Op, out);
}

extern "C" void kernel_launch(void* const* d_in, const int* in_sizes, int n_in,
                              void* d_out, int out_size, void* d_ws, size_t ws_size,
                              hipStream_t stream) {
    const float* z1 = (const float*)d_in[0];
    const float* z2 = (const float*)d_in[1];
    float* out = (float*)d_out;

    char* w = (char*)d_ws;
    unsigned short* Qb2  = (unsigned short*)(w);                 // 1,638,400 B
    unsigned short* Z2s  = (unsigned short*)(w + 1638400);       // 6,553,600 B
    unsigned short* X    = (unsigned short*)(w + 8192000);       // 13,107,200 B
    unsigned short* Atn2 = (unsigned short*)(w + 21299200);      // 1,863,680 B
    float* Sp = (float*)(w + 23162880);                          // 29,818,880 B (8 partials)
    float* Op = (float*)(w + 52981760);                          // 26,214,400 B (8 partials)

    void* args[] = {(void*)&z1, (void*)&z2, (void*)&Qb2, (void*)&Z2s, (void*)&X,
                    (void*)&Atn2, (void*)&Sp, (void*)&Op, (void*)&out};
    hipError_t e = hipLaunchCooperativeKernel((void*)fused_kernel, dim3(GRIDC), dim3(256),
                                              args, 0, stream);
    if (e != hipSuccess) {
        // Fallback: the proven 5-dispatch pipeline (identical math).
        pack_kernel<<<5200, 256, 0, stream>>>(z1, z2, Qb2, Z2s, X);
        gemm1_kernel<<<368, 256, 0, stream>>>(Qb2, X, Sp);
        softmax_kernel<<<160, 256, 0, stream>>>(Sp, Atn2);
        gemm2_kernel<<<320, 256, 0, stream>>>(Atn2, Z2s, Op);
        reduce_kernel<<<800, 256, 0, stream>>>(Op, out);
    }
}

// Round 9
// 173.846 us; speedup vs baseline: 2.3144x; 2.3144x over previous
//
#include <hip/hip_runtime.h>

#define KH_   10
#define KW_   4
#define W_    64
#define K1_   5120       // C*KH*KW
#define WK_   61
#define JP_   5824       // 91*64
#define NZ    819200
#define KS1   8          // k-split gemm1 (chunk 640, 20 iters of 32)
#define KS2   8          // jp-split gemm2

typedef __attribute__((ext_vector_type(8))) short short8;
typedef __attribute__((ext_vector_type(4))) short short4v;
typedef __attribute__((ext_vector_type(4))) float f32x4;

__device__ __forceinline__ unsigned short f2bf(float f) {
    unsigned int u = __float_as_uint(f);
    return (unsigned short)((u + 0x8000u) >> 16);
}

// ---------------------------------------------------------------------------
// pack: Qb2 (Q MFMA-A frags), Z2s (shifted planes), X (row-pair octs),
// plus zero the 40 gemm2 split-K counters (ws is re-poisoned every call).
// units = 1,331,200 + 40 -> grid 5201 x 256
// ---------------------------------------------------------------------------
__global__ __launch_bounds__(256) void pack_kernel(const float* __restrict__ z1,
                                                   const float* __restrict__ z2,
                                                   unsigned short* __restrict__ Qb2,
                                                   unsigned short* __restrict__ Z2s,
                                                   unsigned short* __restrict__ X,
                                                   int* __restrict__ cnt) {
    int tid = blockIdx.x * 256 + threadIdx.x;
    if (tid < 102400) {                       // --- Qb2 octs (frag layout) ---
        int ko = tid / 160, i = tid - ko * 160;
        int d0 = ko * 8;
        int c = d0 / 40, rr = d0 - c * 40;
        int kh0 = rr >> 2;                    // even
        int ih = i >> 4, iw = i & 15;
        int a0 = c * 6400 + (ih * KH_ + kh0) * W_ + iw * KW_;
        unsigned short v[8];
#pragma unroll
        for (int s = 0; s < 4; ++s) v[s] = f2bf(z1[a0 + s]);
#pragma unroll
        for (int s = 0; s < 4; ++s) v[4 + s] = f2bf(z1[a0 + W_ + s]);
        *(short8*)(Qb2 + (size_t)tid * 8) = *(short8*)v;
    } else if (tid < 512000) {                // --- Z2s octs ---
        int o = tid - 102400;
        int kw = o / 102400, r8 = o - kw * 102400;
        int e0 = r8 * 8;
        int w0 = e0 & 63, rowbase = e0 - w0;
        unsigned short v[8];
#pragma unroll
        for (int s = 0; s < 8; ++s) v[s] = f2bf(z2[rowbase + min(w0 + s + kw, 63)]);
        *(short8*)(Z2s + (size_t)kw * NZ + e0) = *(short8*)v;
    } else if (tid < 1331200) {               // --- X octs ---
        int o = tid - 512000;                 // o = (c*100+h)*64 + w
        int w = o & 63, ch = o >> 6;
        int h = ch % 100;
        int ch2 = (h < 99) ? ch + 1 : ch;
        unsigned short v[8];
#pragma unroll
        for (int s = 0; s < 4; ++s) v[s] = f2bf(z2[ch * 64 + min(w + s, 63)]);
#pragma unroll
        for (int s = 0; s < 4; ++s) v[4 + s] = f2bf(z2[ch2 * 64 + min(w + s, 63)]);
        *(short8*)(X + (size_t)o * 8) = *(short8*)v;
    } else if (tid < 1331240) {               // --- zero split-K counters ---
        cnt[tid - 1331200] = 0;
    }
}

// ---------------------------------------------------------------------------
// GEMM1: no LDS, no barriers. grid (KS1, 46) = 368 blocks x 256 thr.
// Tile 160x128 (2 hk bands); wave tile 80x64; all fragment loads coalesced.
// ---------------------------------------------------------------------------
__global__ __launch_bounds__(256) void gemm1_kernel(const unsigned short* __restrict__ Qb2,
                                                    const unsigned short* __restrict__ X,
                                                    float* __restrict__ Sp) {
    const int t = threadIdx.x;
    const int ksp = blockIdx.x;      // 0..7
    const int hkt = blockIdx.y;      // 0..45
    const int hk0 = hkt * 2;
    const int wave = t >> 6, lane = t & 63;
    const int mh = wave & 1, nh = wave >> 1;       // wave tile 80 x 64
    const int l15 = lane & 15, q = lane >> 4;

    int band[4], wk[4];
#pragma unroll
    for (int n = 0; n < 4; ++n) {
        int jpn = (nh * 4 + n) * 16 + l15;
        band[n] = jpn >> 6;
        wk[n]   = jpn & 63;
    }
    int rowA[5];
#pragma unroll
    for (int b = 0; b < 5; ++b) rowA[b] = (mh * 5 + b) * 16 + l15;

    f32x4 acc[5][4];
#pragma unroll
    for (int b = 0; b < 5; ++b)
#pragma unroll
        for (int n = 0; n < 4; ++n) acc[b][n] = (f32x4){0.f, 0.f, 0.f, 0.f};

    for (int it = 0; it < 20; ++it) {
        const unsigned short* Ab = Qb2 + ((size_t)(ksp * 80 + it * 4 + q) * 160) * 8;
        short8 af[5], bf[4];
#pragma unroll
        for (int b = 0; b < 5; ++b)
            af[b] = *(const short8*)(Ab + rowA[b] * 8);
        int d0 = ksp * 640 + it * 32 + q * 8;
        unsigned du = (unsigned)d0;
        int c = du / 40u, rr = d0 - c * 40;
        int kh0 = rr >> 2;           // even
        const unsigned short* Bb = X + ((size_t)(c * 100 + hk0 + kh0) * 64) * 8;
#pragma unroll
        for (int n = 0; n < 4; ++n)
            bf[n] = *(const short8*)(Bb + (band[n] * 64 + wk[n]) * 8);
#pragma unroll
        for (int b = 0; b < 5; ++b)
#pragma unroll
            for (int n = 0; n < 4; ++n)
                acc[b][n] = __builtin_amdgcn_mfma_f32_16x16x32_bf16(af[b], bf[n], acc[b][n], 0, 0, 0);
    }
    float* base = Sp + (size_t)ksp * (160 * JP_);
#pragma unroll
    for (int b = 0; b < 5; ++b) {
        int i0 = (mh * 5 + b) * 16 + q * 4;
#pragma unroll
        for (int n = 0; n < 4; ++n) {
            int jg = hkt * 128 + (nh * 4 + n) * 16 + l15;
            if (jg < JP_) {
#pragma unroll
                for (int r = 0; r < 4; ++r)
                    base[(size_t)(i0 + r) * JP_ + jg] = acc[b][n][r];
            }
        }
    }
}

// ---------------------------------------------------------------------------
// softmax: per q-row; sums KS1 partials; no max-pass (|s| small); masks pad
// cols; writes Atn2 in MFMA-B fragment layout [jp_oct][i][8].
// ---------------------------------------------------------------------------
__global__ __launch_bounds__(256) void softmax_kernel(const float* __restrict__ Sp,
                                                      unsigned short* __restrict__ Atn2) {
    const int i = blockIdx.x;
    const int t = threadIdx.x;
    const int wave = t >> 6, lane = t & 63;
    __shared__ float red2[4];
    f32x4 v[6];
    float s = 0.f;
#pragma unroll
    for (int jj = 0; jj < 6; ++jj) {
        int q4 = t + jj * 256;
        f32x4 r = (f32x4){0.f, 0.f, 0.f, 0.f};
        if (q4 < 1456) {
            f32x4 a = (f32x4){0.f, 0.f, 0.f, 0.f};
#pragma unroll
            for (int p = 0; p < KS1; ++p)
                a += *(const f32x4*)(Sp + (size_t)p * (160 * JP_) + (size_t)i * JP_ + q4 * 4);
            a *= (1.0f / 5120.0f);
            bool pad_hi = (((q4 * 4) & 63) == 60);  // cols 61,62,63 of a band
#pragma unroll
            for (int e = 0; e < 4; ++e) {
                bool ok = !(pad_hi && e > 0);
                float x = ok ? __expf(a[e]) : 0.f;
                r[e] = x;
                s += x;
            }
        }
        v[jj] = r;
    }
#pragma unroll
    for (int off = 32; off >= 1; off >>= 1) s += __shfl_xor(s, off);
    if (lane == 0) red2[wave] = s;
    __syncthreads();
    float inv = 1.0f / (red2[0] + red2[1] + red2[2] + red2[3]);
#pragma unroll
    for (int jj = 0; jj < 6; ++jj) {
        int q4 = t + jj * 256;
        if (q4 < 1456) {
            short4v u;
            u.x = (short)f2bf(v[jj].x * inv);
            u.y = (short)f2bf(v[jj].y * inv);
            u.z = (short)f2bf(v[jj].z * inv);
            u.w = (short)f2bf(v[jj].w * inv);
            *(short4v*)(Atn2 + ((size_t)(q4 >> 1) * 160 + i) * 8 + (q4 & 1) * 4) = u;
        }
    }
}

// ---------------------------------------------------------------------------
// GEMM2 + fused split-K reduce: grid (KS2, 40); tile 128(d) x 160(i).
// KV^T staged via LDS; attn B-frags direct from Atn2. Each block stores its
// fp32 partial, then ACQ_REL fetch-adds cnt[dt]; the 8th finisher re-reads
// all 8 partials and writes `out` (the R6 reduce_kernel inlined). No spin,
// deadlock-free; counters zeroed by pack each call.
// ---------------------------------------------------------------------------
__global__ __launch_bounds__(256) void gemm2_kernel(const unsigned short* __restrict__ Atn2,
                                                    const unsigned short* __restrict__ Z2s,
                                                    float* __restrict__ Op,
                                                    int* __restrict__ cnt,
                                                    float* __restrict__ out) {
    __shared__ short As[128 * 40];   // KV^T tile [d_local][jp_local], stride 40 (2-way, free)
    __shared__ int ticket_s;
    const int t = threadIdx.x;
    const int ksp = blockIdx.x;      // 0..7
    const int dt = blockIdx.y;       // 0..39
    const int dbase = dt * 128;
    const int it0 = (182 * ksp) >> 3;
    const int it1 = (182 * (ksp + 1)) >> 3;
    const int wave = t >> 6, lane = t & 63;
    const int mh = wave & 1, nh = wave >> 1;       // wave tile 64(d) x 80(i)
    const int l15 = lane & 15, q = lane >> 4;

    const int dl_s = t >> 2, jg_s = t & 3;
    f32x4 acc[4][5];
#pragma unroll
    for (int m = 0; m < 4; ++m)
#pragma unroll
        for (int n = 0; n < 5; ++n) acc[m][n] = (f32x4){0.f, 0.f, 0.f, 0.f};

    for (int it = it0; it < it1; ++it) {
        int k0 = it * 32;
        __syncthreads();
#pragma unroll
        for (int s = 0; s < 2; ++s) {
            int dl = dl_s + s * 64, jg = jg_s;
            int d = dbase + dl;
            unsigned du = (unsigned)d;
            int c = du / 40u, rr = d - c * 40;
            int kh = rr >> 2, kw = rr & 3;
            int jp0 = k0 + jg * 8;
            int hk = jp0 >> 6, wk0 = jp0 & 63;
            int src = kw * NZ + c * 6400 + (hk + kh) * W_ + wk0;
            *(short8*)&As[dl * 40 + jg * 8] = *(const short8*)(Z2s + src);
        }
        __syncthreads();
        short8 af[4], bf[5];
#pragma unroll
        for (int m = 0; m < 4; ++m)
            af[m] = *(const short8*)&As[(mh * 64 + m * 16 + l15) * 40 + q * 8];
        const unsigned short* Bb = Atn2 + ((size_t)((k0 >> 3) + q) * 160) * 8;
#pragma unroll
        for (int n = 0; n < 5; ++n)
            bf[n] = *(const short8*)(Bb + ((nh * 5 + n) * 16 + l15) * 8);
#pragma unroll
        for (int m = 0; m < 4; ++m)
#pragma unroll
            for (int n = 0; n < 5; ++n)
                acc[m][n] = __builtin_amdgcn_mfma_f32_16x16x32_bf16(af[m], bf[n], acc[m][n], 0, 0, 0);
    }
    // store this split's partial
    float* base = Op + (size_t)ksp * ((size_t)NZ);
#pragma unroll
    for (int m = 0; m < 4; ++m) {
        int d0 = dbase + mh * 64 + m * 16 + q * 4;
#pragma unroll
        for (int n = 0; n < 5; ++n) {
            int i = (nh * 5 + n) * 16 + l15;
#pragma unroll
            for (int r = 0; r < 4; ++r)
                base[(size_t)(d0 + r) * 160 + i] = acc[m][n][r];
        }
    }
    // split-K completion ticket (release our stores / acquire others')
    __syncthreads();
    if (t == 0)
        ticket_s = __hip_atomic_fetch_add(&cnt[dt], 1, __ATOMIC_ACQ_REL,
                                          __HIP_MEMORY_SCOPE_AGENT);
    __syncthreads();
    if (ticket_s == KS2 - 1) {
        // we are the last split for this dt: reduce 8 partials -> out
        for (int u = t; u < 5120; u += 256) {       // 128 d x 40 i-quads
            int dloc = u / 40, i4 = u - dloc * 40;
            int d = dbase + dloc;
            int f = d * 160 + i4 * 4;
            f32x4 s = (f32x4){0.f, 0.f, 0.f, 0.f};
#pragma unroll
            for (int p = 0; p < KS2; ++p)
                s += *(const f32x4*)(Op + (size_t)p * NZ + f);
            int c = d / 40, rr = d - c * 40;
            int kh = rr >> 2, kw = rr & 3;
#pragma unroll
            for (int r = 0; r < 4; ++r) {
                int i = i4 * 4 + r;
                int ih = i >> 4, iw = i & 15;
                out[c * 6400 + (ih * KH_ + kh) * W_ + iw * KW_ + kw] = s[r];
            }
        }
    }
}

extern "C" void kernel_launch(void* const* d_in, const int* in_sizes, int n_in,
                              void* d_out, int out_size, void* d_ws, size_t ws_size,
                              hipStream_t stream) {
    const float* z1 = (const float*)d_in[0];
    const float* z2 = (const float*)d_in[1];
    float* out = (float*)d_out;

    char* w = (char*)d_ws;
    unsigned short* Qb2  = (unsigned short*)(w);                 // 1,638,400 B
    unsigned short* Z2s  = (unsigned short*)(w + 1638400);       // 6,553,600 B
    unsigned short* X    = (unsigned short*)(w + 8192000);       // 13,107,200 B
    unsigned short* Atn2 = (unsigned short*)(w + 21299200);      // 1,863,680 B
    float* Sp = (float*)(w + 23162880);                          // 29,818,880 B (8 partials)
    float* Op = (float*)(w + 52981760);                          // 26,214,400 B (8 partials)
    int*   cnt = (int*)(w + 79196160);                           // 160 B (40 counters)

    pack_kernel<<<5201, 256, 0, stream>>>(z1, z2, Qb2, Z2s, X, cnt);
    gemm1_kernel<<<dim3(KS1, 46), 256, 0, stream>>>(Qb2, X, Sp);
    softmax_kernel<<<160, 256, 0, stream>>>(Sp, Atn2);
    gemm2_kernel<<<dim3(KS2, 40), 256, 0, stream>>>(Atn2, Z2s, Op, cnt, out);
}

// Round 10
// 140.506 us; speedup vs baseline: 2.8636x; 1.2373x over previous
//
#include <hip/hip_runtime.h>
#include <hip/hip_fp16.h>

#define KH_   10
#define KW_   4
#define W_    64
#define K1_   5120       // C*KH*KW
#define WK_   61
#define JP_   5824       // 91*64
#define NZ    819200
#define KS1   16         // k-split gemm1 (chunk 320, 10 iters of 32)
#define KS2   16         // jp-split gemm2 (182 iters split 11/12)

typedef __attribute__((ext_vector_type(8))) short short8;
typedef __attribute__((ext_vector_type(8))) unsigned short ushort8;
typedef __attribute__((ext_vector_type(4))) float f32x4;

__device__ __forceinline__ unsigned short f2bf(float f) {
    unsigned int u = __float_as_uint(f);
    return (unsigned short)((u + 0x8000u) >> 16);
}
__device__ __forceinline__ unsigned short f2h(float f) {
    return __half_as_ushort(__float2half(f));
}
__device__ __forceinline__ float h2f(unsigned short u) {
    return __half2float(__ushort_as_half(u));
}

// ---------------------------------------------------------------------------
// pack: Qb2 (Q MFMA-A frags), Z2s (shifted planes), X (row-pair octs).
// 1,331,200 units -> grid 5200 x 256   (unchanged, proven)
// ---------------------------------------------------------------------------
__global__ __launch_bounds__(256) void pack_kernel(const float* __restrict__ z1,
                                                   const float* __restrict__ z2,
                                                   unsigned short* __restrict__ Qb2,
                                                   unsigned short* __restrict__ Z2s,
                                                   unsigned short* __restrict__ X) {
    int tid = blockIdx.x * 256 + threadIdx.x;
    if (tid < 102400) {                       // --- Qb2 octs (frag layout) ---
        int ko = tid / 160, i = tid - ko * 160;
        int d0 = ko * 8;
        int c = d0 / 40, rr = d0 - c * 40;
        int kh0 = rr >> 2;                    // even
        int ih = i >> 4, iw = i & 15;
        int a0 = c * 6400 + (ih * KH_ + kh0) * W_ + iw * KW_;
        unsigned short v[8];
#pragma unroll
        for (int s = 0; s < 4; ++s) v[s] = f2bf(z1[a0 + s]);
#pragma unroll
        for (int s = 0; s < 4; ++s) v[4 + s] = f2bf(z1[a0 + W_ + s]);
        *(short8*)(Qb2 + (size_t)tid * 8) = *(short8*)v;
    } else if (tid < 512000) {                // --- Z2s octs ---
        int o = tid - 102400;
        int kw = o / 102400, r8 = o - kw * 102400;
        int e0 = r8 * 8;
        int w0 = e0 & 63, rowbase = e0 - w0;
        unsigned short v[8];
#pragma unroll
        for (int s = 0; s < 8; ++s) v[s] = f2bf(z2[rowbase + min(w0 + s + kw, 63)]);
        *(short8*)(Z2s + (size_t)kw * NZ + e0) = *(short8*)v;
    } else {                                  // --- X octs ---
        int o = tid - 512000;                 // o = (c*100+h)*64 + w
        int w = o & 63, ch = o >> 6;
        int h = ch % 100;
        int ch2 = (h < 99) ? ch + 1 : ch;
        unsigned short v[8];
#pragma unroll
        for (int s = 0; s < 4; ++s) v[s] = f2bf(z2[ch * 64 + min(w + s, 63)]);
#pragma unroll
        for (int s = 0; s < 4; ++s) v[4 + s] = f2bf(z2[ch2 * 64 + min(w + s, 63)]);
        *(short8*)(X + (size_t)o * 8) = *(short8*)v;
    }
}

// ---------------------------------------------------------------------------
// GEMM1: no LDS, no barriers. grid (KS1=16, 46) = 736 blocks (2.9/CU).
// Tile 160x128 (2 hk bands); wave tile 80x64; all fragment loads coalesced.
// Epilogue writes fp16 partials.
// ---------------------------------------------------------------------------
__global__ __launch_bounds__(256) void gemm1_kernel(const unsigned short* __restrict__ Qb2,
                                                    const unsigned short* __restrict__ X,
                                                    unsigned short* __restrict__ Sph) {
    const int t = threadIdx.x;
    const int ksp = blockIdx.x;      // 0..15
    const int hkt = blockIdx.y;      // 0..45
    const int hk0 = hkt * 2;
    const int wave = t >> 6, lane = t & 63;
    const int mh = wave & 1, nh = wave >> 1;       // wave tile 80 x 64
    const int l15 = lane & 15, q = lane >> 4;

    int band[4], wk[4];
#pragma unroll
    for (int n = 0; n < 4; ++n) {
        int jpn = (nh * 4 + n) * 16 + l15;
        band[n] = jpn >> 6;
        wk[n]   = jpn & 63;
    }
    int rowA[5];
#pragma unroll
    for (int b = 0; b < 5; ++b) rowA[b] = (mh * 5 + b) * 16 + l15;

    f32x4 acc[5][4];
#pragma unroll
    for (int b = 0; b < 5; ++b)
#pragma unroll
        for (int n = 0; n < 4; ++n) acc[b][n] = (f32x4){0.f, 0.f, 0.f, 0.f};

    for (int it = 0; it < 10; ++it) {
        const unsigned short* Ab = Qb2 + ((size_t)(ksp * 40 + it * 4 + q) * 160) * 8;
        short8 af[5], bf[4];
#pragma unroll
        for (int b = 0; b < 5; ++b)
            af[b] = *(const short8*)(Ab + rowA[b] * 8);
        int d0 = ksp * 320 + it * 32 + q * 8;
        unsigned du = (unsigned)d0;
        int c = du / 40u, rr = d0 - c * 40;
        int kh0 = rr >> 2;           // even
        const unsigned short* Bb = X + ((size_t)(c * 100 + hk0 + kh0) * 64) * 8;
#pragma unroll
        for (int n = 0; n < 4; ++n)
            bf[n] = *(const short8*)(Bb + (band[n] * 64 + wk[n]) * 8);
#pragma unroll
        for (int b = 0; b < 5; ++b)
#pragma unroll
            for (int n = 0; n < 4; ++n)
                acc[b][n] = __builtin_amdgcn_mfma_f32_16x16x32_bf16(af[b], bf[n], acc[b][n], 0, 0, 0);
    }
    unsigned short* base = Sph + (size_t)ksp * (160 * JP_);
#pragma unroll
    for (int b = 0; b < 5; ++b) {
        int i0 = (mh * 5 + b) * 16 + q * 4;
#pragma unroll
        for (int n = 0; n < 4; ++n) {
            int jg = hkt * 128 + (nh * 4 + n) * 16 + l15;
            if (jg < JP_) {
#pragma unroll
                for (int r = 0; r < 4; ++r)
                    base[(size_t)(i0 + r) * JP_ + jg] = f2h(acc[b][n][r]);
            }
        }
    }
}

// ---------------------------------------------------------------------------
// softmax: per q-row; sums 16 fp16 partials (ushort8 loads, 8 jp/thread);
// no max-pass (|s| small); masks pad cols; writes Atn2 bf16 MFMA-B frags.
// grid 160 x 256.
// ---------------------------------------------------------------------------
__global__ __launch_bounds__(256) void softmax_kernel(const unsigned short* __restrict__ Sph,
                                                      unsigned short* __restrict__ Atn2) {
    const int i = blockIdx.x;
    const int t = threadIdx.x;
    const int wave = t >> 6, lane = t & 63;
    __shared__ float red2[4];
    float v[3][8];
    float s = 0.f;
#pragma unroll
    for (int jj = 0; jj < 3; ++jj) {
        int o8 = t + jj * 256;              // jp oct, 728 total
#pragma unroll
        for (int e = 0; e < 8; ++e) v[jj][e] = 0.f;
        if (o8 < 728) {
            float a[8];
#pragma unroll
            for (int e = 0; e < 8; ++e) a[e] = 0.f;
#pragma unroll
            for (int p = 0; p < KS1; ++p) {
                ushort8 h = *(const ushort8*)(Sph + (size_t)p * (160 * JP_) + (size_t)i * JP_ + o8 * 8);
#pragma unroll
                for (int e = 0; e < 8; ++e) a[e] += h2f(h[e]);
            }
            bool tail = (o8 & 7) == 7;      // jp%64 = 56+e -> e>=5 are pad cols
#pragma unroll
            for (int e = 0; e < 8; ++e) {
                bool ok = !(tail && e >= 5);
                float x = ok ? __expf(a[e] * (1.0f / 5120.0f)) : 0.f;
                v[jj][e] = x;
                s += x;
            }
        }
    }
#pragma unroll
    for (int off = 32; off >= 1; off >>= 1) s += __shfl_xor(s, off);
    if (lane == 0) red2[wave] = s;
    __syncthreads();
    float inv = 1.0f / (red2[0] + red2[1] + red2[2] + red2[3]);
#pragma unroll
    for (int jj = 0; jj < 3; ++jj) {
        int o8 = t + jj * 256;
        if (o8 < 728) {
            unsigned short u[8];
#pragma unroll
            for (int e = 0; e < 8; ++e) u[e] = f2bf(v[jj][e] * inv);
            *(short8*)(Atn2 + ((size_t)o8 * 160 + i) * 8) = *(short8*)u;
        }
    }
}

// ---------------------------------------------------------------------------
// GEMM2: grid (KS2=16, 40) = 640 blocks (2.5/CU); tile 128(d) x 160(i).
// KV^T staged via DOUBLE-BUFFERED LDS (one barrier/iter, prefetch overlaps
// MFMA); attn B-frags direct from Atn2 (coalesced). fp16 partials Oph.
// ---------------------------------------------------------------------------
__global__ __launch_bounds__(256) void gemm2_kernel(const unsigned short* __restrict__ Atn2,
                                                    const unsigned short* __restrict__ Z2s,
                                                    unsigned short* __restrict__ Oph) {
    __shared__ short As[2][128 * 40];   // stride 40 shorts (2-way, free)
    const int t = threadIdx.x;
    const int ksp = blockIdx.x;      // 0..15
    const int dt = blockIdx.y;       // 0..39
    const int dbase = dt * 128;
    const int it0 = (182 * ksp) >> 4;
    const int it1 = (182 * (ksp + 1)) >> 4;
    const int wave = t >> 6, lane = t & 63;
    const int mh = wave & 1, nh = wave >> 1;       // wave tile 64(d) x 80(i)
    const int l15 = lane & 15, q = lane >> 4;

    const int dl_s = t >> 2, jg_s = t & 3;
    // lane-invariant staging address parts (d-dependent)
    int sb0, sb1;
    {
        int d = dbase + dl_s;
        unsigned du = (unsigned)d;
        int c = du / 40u, rr = d - c * 40;
        sb0 = (rr & 3) * NZ + c * 6400 + (rr >> 2) * W_;
        d = dbase + dl_s + 64;
        du = (unsigned)d;
        c = du / 40u; rr = d - c * 40;
        sb1 = (rr & 3) * NZ + c * 6400 + (rr >> 2) * W_;
    }

    f32x4 acc[4][5];
#pragma unroll
    for (int m = 0; m < 4; ++m)
#pragma unroll
        for (int n = 0; n < 5; ++n) acc[m][n] = (f32x4){0.f, 0.f, 0.f, 0.f};

    auto load_regs = [&](int it, short8& r0, short8& r1) {
        int jp0 = it * 32 + jg_s * 8;
        int off = (jp0 >> 6) * W_ + (jp0 & 63);
        r0 = *(const short8*)(Z2s + sb0 + off);
        r1 = *(const short8*)(Z2s + sb1 + off);
    };
    auto write_lds = [&](int p, short8 r0, short8 r1) {
        *(short8*)&As[p][dl_s * 40 + jg_s * 8] = r0;
        *(short8*)&As[p][(dl_s + 64) * 40 + jg_s * 8] = r1;
    };

    short8 r0, r1;
    load_regs(it0, r0, r1);
    write_lds(0, r0, r1);
    __syncthreads();

    for (int it = it0; it < it1; ++it) {
        int p = (it - it0) & 1;
        short8 n0, n1;
        bool more = (it + 1 < it1);
        if (more) load_regs(it + 1, n0, n1);

        short8 af[4], bf[5];
#pragma unroll
        for (int m = 0; m < 4; ++m)
            af[m] = *(const short8*)&As[p][(mh * 64 + m * 16 + l15) * 40 + q * 8];
        const unsigned short* Bb = Atn2 + ((size_t)(it * 4 + q) * 160) * 8;
#pragma unroll
        for (int n = 0; n < 5; ++n)
            bf[n] = *(const short8*)(Bb + ((nh * 5 + n) * 16 + l15) * 8);
#pragma unroll
        for (int m = 0; m < 4; ++m)
#pragma unroll
            for (int n = 0; n < 5; ++n)
                acc[m][n] = __builtin_amdgcn_mfma_f32_16x16x32_bf16(af[m], bf[n], acc[m][n], 0, 0, 0);

        if (more) write_lds(p ^ 1, n0, n1);
        __syncthreads();
    }
    unsigned short* base = Oph + (size_t)ksp * ((size_t)NZ);
#pragma unroll
    for (int m = 0; m < 4; ++m) {
        int d0 = dbase + mh * 64 + m * 16 + q * 4;
#pragma unroll
        for (int n = 0; n < 5; ++n) {
            int i = (nh * 5 + n) * 16 + l15;
#pragma unroll
            for (int r = 0; r < 4; ++r)
                base[(size_t)(d0 + r) * 160 + i] = f2h(acc[m][n][r]);
        }
    }
}

// ---------------------------------------------------------------------------
// reduce: out = sum of 16 fp16 partials; 8 elems/thread; grid 400 x 256.
// ---------------------------------------------------------------------------
__global__ __launch_bounds__(256) void reduce_kernel(const unsigned short* __restrict__ Oph,
                                                     float* __restrict__ out) {
    int tid = blockIdx.x * 256 + threadIdx.x;   // < 102400
    int f = tid * 8;
    float s[8];
#pragma unroll
    for (int e = 0; e < 8; ++e) s[e] = 0.f;
#pragma unroll
    for (int p = 0; p < KS2; ++p) {
        ushort8 h = *(const ushort8*)(Oph + (size_t)p * NZ + f);
#pragma unroll
        for (int e = 0; e < 8; ++e) s[e] += h2f(h[e]);
    }
    int d = f / 160, i0 = f - d * 160;          // 8-run stays within one d
    int c = d / 40, rr = d - c * 40;
    int kh = rr >> 2, kw = rr & 3;
    int obase = c * 6400 + kh * W_ + kw;
#pragma unroll
    for (int e = 0; e < 8; ++e) {
        int i = i0 + e;
        int ih = i >> 4, iw = i & 15;
        out[obase + ih * (KH_ * W_) + iw * KW_] = s[e];
    }
}

extern "C" void kernel_launch(void* const* d_in, const int* in_sizes, int n_in,
                              void* d_out, int out_size, void* d_ws, size_t ws_size,
                              hipStream_t stream) {
    const float* z1 = (const float*)d_in[0];
    const float* z2 = (const float*)d_in[1];
    float* out = (float*)d_out;

    char* w = (char*)d_ws;
    unsigned short* Qb2  = (unsigned short*)(w);                 // 1,638,400 B
    unsigned short* Z2s  = (unsigned short*)(w + 1638400);       // 6,553,600 B
    unsigned short* X    = (unsigned short*)(w + 8192000);       // 13,107,200 B
    unsigned short* Atn2 = (unsigned short*)(w + 21299200);      // 1,863,680 B
    unsigned short* Sph  = (unsigned short*)(w + 23162880);      // 29,818,880 B (16 fp16 partials)
    unsigned short* Oph  = (unsigned short*)(w + 52981760);      // 26,214,400 B (16 fp16 partials)

    pack_kernel<<<5200, 256, 0, stream>>>(z1, z2, Qb2, Z2s, X);
    gemm1_kernel<<<dim3(KS1, 46), 256, 0, stream>>>(Qb2, X, Sph);
    softmax_kernel<<<160, 256, 0, stream>>>(Sph, Atn2);
    gemm2_kernel<<<dim3(KS2, 40), 256, 0, stream>>>(Atn2, Z2s, Oph);
    reduce_kernel<<<400, 256, 0, stream>>>(Oph, out);
}

// Round 11
// 140.425 us; speedup vs baseline: 2.8652x; 1.0006x over previous
//
#include <hip/hip_runtime.h>
#include <hip/hip_fp16.h>

#define KH_   10
#define KW_   4
#define W_    64
#define K1_   5120       // C*KH*KW
#define WK_   61
#define JP_   5824       // 91*64
#define NZ    819200
#define KS1   16         // k-split gemm1 (chunk 320, 10 iters of 32)
#define KS2   16         // jp-split gemm2 (182 iters split 11/12)

typedef __attribute__((ext_vector_type(8))) short short8;
typedef __attribute__((ext_vector_type(8))) unsigned short ushort8;
typedef __attribute__((ext_vector_type(4))) float f32x4;

__device__ __forceinline__ unsigned short f2bf(float f) {
    unsigned int u = __float_as_uint(f);
    return (unsigned short)((u + 0x8000u) >> 16);
}
__device__ __forceinline__ unsigned short f2h(float f) {
    return __half_as_ushort(__float2half(f));
}
__device__ __forceinline__ float h2f(unsigned short u) {
    return __half2float(__ushort_as_half(u));
}
__device__ __forceinline__ f32x4 load4u(const float* p) {
    f32x4 v; __builtin_memcpy(&v, p, 16); return v;
}

// ---------------------------------------------------------------------------
// pack: Qb2 (Q MFMA-A frags) + X (row-pair octs). Z2s eliminated (gemm2 now
// stages straight from z2). 921,600 units -> grid 3600 x 256.
// ---------------------------------------------------------------------------
__global__ __launch_bounds__(256) void pack_kernel(const float* __restrict__ z1,
                                                   const float* __restrict__ z2,
                                                   unsigned short* __restrict__ Qb2,
                                                   unsigned short* __restrict__ X) {
    int tid = blockIdx.x * 256 + threadIdx.x;
    if (tid < 102400) {                       // --- Qb2 octs (frag layout) ---
        int ko = tid / 160, i = tid - ko * 160;
        int d0 = ko * 8;
        int c = d0 / 40, rr = d0 - c * 40;
        int kh0 = rr >> 2;                    // even
        int ih = i >> 4, iw = i & 15;
        int a0 = c * 6400 + (ih * KH_ + kh0) * W_ + iw * KW_;
        unsigned short v[8];
#pragma unroll
        for (int s = 0; s < 4; ++s) v[s] = f2bf(z1[a0 + s]);
#pragma unroll
        for (int s = 0; s < 4; ++s) v[4 + s] = f2bf(z1[a0 + W_ + s]);
        *(short8*)(Qb2 + (size_t)tid * 8) = *(short8*)v;
    } else {                                  // --- X octs ---
        int o = tid - 102400;                 // o = (c*100+h)*64 + w
        int w = o & 63, ch = o >> 6;
        int h = ch % 100;
        int ch2 = (h < 99) ? ch + 1 : ch;
        unsigned short v[8];
#pragma unroll
        for (int s = 0; s < 4; ++s) v[s] = f2bf(z2[ch * 64 + min(w + s, 63)]);
#pragma unroll
        for (int s = 0; s < 4; ++s) v[4 + s] = f2bf(z2[ch2 * 64 + min(w + s, 63)]);
        *(short8*)(X + (size_t)o * 8) = *(short8*)v;
    }
}

// ---------------------------------------------------------------------------
// GEMM1: grid (KS1=16, 46) = 736 blocks; tile 160x128, wave tile 80x64.
// NEW: A and B staged once per iter through double-buffered LDS (stride 40
// shorts = 20 dw: bank-cycle-complete, conflict-free for b128) — halves the
// L2 traffic vs direct fragment loads (which read every element twice).
// ---------------------------------------------------------------------------
__global__ __launch_bounds__(256) void gemm1_kernel(const unsigned short* __restrict__ Qb2,
                                                    const unsigned short* __restrict__ X,
                                                    unsigned short* __restrict__ Sph) {
    __shared__ short As1[2][160 * 40];   // Q tile  [row][koct*8]
    __shared__ short Bs1[2][128 * 40];   // KV tile [jp][koct*8]
    const int t = threadIdx.x;
    const int ksp = blockIdx.x;      // 0..15
    const int hkt = blockIdx.y;      // 0..45
    const int hk0 = hkt * 2;
    const int wave = t >> 6, lane = t & 63;
    const int mh = wave & 1, nh = wave >> 1;       // wave tile 80 x 64
    const int l15 = lane & 15, q = lane >> 4;

    f32x4 acc[5][4];
#pragma unroll
    for (int b = 0; b < 5; ++b)
#pragma unroll
        for (int n = 0; n < 4; ++n) acc[b][n] = (f32x4){0.f, 0.f, 0.f, 0.f};

    // staging: A 640 units (u = row*4 + koct), B 512 units (u = koct*128 + jp)
    auto loadA = [&](int it, short8* pa) {
        int kb = ksp * 40 + it * 4;
#pragma unroll
        for (int s = 0; s < 3; ++s) {
            int u = t + s * 256;
            if (u < 640)
                pa[s] = *(const short8*)(Qb2 + ((size_t)(kb + (u & 3)) * 160 + (u >> 2)) * 8);
        }
    };
    auto loadB = [&](int it, short8* pb) {
        int d0b = ksp * 320 + it * 32;
#pragma unroll
        for (int s = 0; s < 2; ++s) {
            int u = t + s * 256;
            int jp = u & 127, koct = u >> 7;
            int d0 = d0b + koct * 8;
            unsigned du = (unsigned)d0;
            int c = du / 40u, rr = d0 - c * 40;
            int kh0 = rr >> 2;               // even
            pb[s] = *(const short8*)(X + ((size_t)((c * 100 + hk0 + (jp >> 6) + kh0) * 64 + (jp & 63))) * 8);
        }
    };
    auto writeAB = [&](int p, const short8* pa, const short8* pb) {
#pragma unroll
        for (int s = 0; s < 3; ++s) {
            int u = t + s * 256;
            if (u < 640) *(short8*)&As1[p][(u >> 2) * 40 + (u & 3) * 8] = pa[s];
        }
#pragma unroll
        for (int s = 0; s < 2; ++s) {
            int u = t + s * 256;
            *(short8*)&Bs1[p][(u & 127) * 40 + (u >> 7) * 8] = pb[s];
        }
    };

    short8 pa[3], pb[2];
    loadA(0, pa); loadB(0, pb);
    writeAB(0, pa, pb);
    __syncthreads();

    for (int it = 0; it < 10; ++it) {
        int p = it & 1;
        bool more = (it + 1 < 10);
        if (more) { loadA(it + 1, pa); loadB(it + 1, pb); }
        short8 af[5], bf[4];
#pragma unroll
        for (int b = 0; b < 5; ++b)
            af[b] = *(const short8*)&As1[p][((mh * 5 + b) * 16 + l15) * 40 + q * 8];
#pragma unroll
        for (int n = 0; n < 4; ++n)
            bf[n] = *(const short8*)&Bs1[p][((nh * 4 + n) * 16 + l15) * 40 + q * 8];
#pragma unroll
        for (int b = 0; b < 5; ++b)
#pragma unroll
            for (int n = 0; n < 4; ++n)
                acc[b][n] = __builtin_amdgcn_mfma_f32_16x16x32_bf16(af[b], bf[n], acc[b][n], 0, 0, 0);
        if (more) writeAB(p ^ 1, pa, pb);
        __syncthreads();
    }
    unsigned short* base = Sph + (size_t)ksp * (160 * JP_);
#pragma unroll
    for (int b = 0; b < 5; ++b) {
        int i0 = (mh * 5 + b) * 16 + q * 4;
#pragma unroll
        for (int n = 0; n < 4; ++n) {
            int jg = hkt * 128 + (nh * 4 + n) * 16 + l15;
            if (jg < JP_) {
#pragma unroll
                for (int r = 0; r < 4; ++r)
                    base[(size_t)(i0 + r) * JP_ + jg] = f2h(acc[b][n][r]);
            }
        }
    }
}

// ---------------------------------------------------------------------------
// softmax: per q-row; sums 16 fp16 partials; no max-pass; masks pad cols;
// writes Atn2 bf16 MFMA-B frags [jp_oct][i][8]. grid 160 x 256. (R10 proven)
// ---------------------------------------------------------------------------
__global__ __launch_bounds__(256) void softmax_kernel(const unsigned short* __restrict__ Sph,
                                                      unsigned short* __restrict__ Atn2) {
    const int i = blockIdx.x;
    const int t = threadIdx.x;
    const int wave = t >> 6, lane = t & 63;
    __shared__ float red2[4];
    float v[3][8];
    float s = 0.f;
#pragma unroll
    for (int jj = 0; jj < 3; ++jj) {
        int o8 = t + jj * 256;              // jp oct, 728 total
#pragma unroll
        for (int e = 0; e < 8; ++e) v[jj][e] = 0.f;
        if (o8 < 728) {
            float a[8];
#pragma unroll
            for (int e = 0; e < 8; ++e) a[e] = 0.f;
#pragma unroll
            for (int p = 0; p < KS1; ++p) {
                ushort8 h = *(const ushort8*)(Sph + (size_t)p * (160 * JP_) + (size_t)i * JP_ + o8 * 8);
#pragma unroll
                for (int e = 0; e < 8; ++e) a[e] += h2f(h[e]);
            }
            bool tail = (o8 & 7) == 7;      // jp%64 = 56+e -> e>=5 are pad cols
#pragma unroll
            for (int e = 0; e < 8; ++e) {
                bool ok = !(tail && e >= 5);
                float x = ok ? __expf(a[e] * (1.0f / 5120.0f)) : 0.f;
                v[jj][e] = x;
                s += x;
            }
        }
    }
#pragma unroll
    for (int off = 32; off >= 1; off >>= 1) s += __shfl_xor(s, off);
    if (lane == 0) red2[wave] = s;
    __syncthreads();
    float inv = 1.0f / (red2[0] + red2[1] + red2[2] + red2[3]);
#pragma unroll
    for (int jj = 0; jj < 3; ++jj) {
        int o8 = t + jj * 256;
        if (o8 < 728) {
            unsigned short u[8];
#pragma unroll
            for (int e = 0; e < 8; ++e) u[e] = f2bf(v[jj][e] * inv);
            *(short8*)(Atn2 + ((size_t)o8 * 160 + i) * 8) = *(short8*)u;
        }
    }
}

// ---------------------------------------------------------------------------
// GEMM2: grid (KS2=16, 40); tile 128(d) x 160(i). NEW: KV^T staged straight
// from fp32 z2 (cvt in staging — Z2s buffer eliminated); attn ALSO staged
// through LDS (halves Atn2 L2 reads). Both double-buffered, one barrier/iter.
// fp16 partials Oph.
// ---------------------------------------------------------------------------
__global__ __launch_bounds__(256) void gemm2_kernel(const unsigned short* __restrict__ Atn2,
                                                    const float* __restrict__ z2,
                                                    unsigned short* __restrict__ Oph) {
    __shared__ short As[2][128 * 40];   // KV^T tile [d_local][jl]
    __shared__ short Bs[2][160 * 40];   // attn tile [i][jl]
    const int t = threadIdx.x;
    const int ksp = blockIdx.x;      // 0..15
    const int dt = blockIdx.y;       // 0..39
    const int dbase = dt * 128;
    const int it0 = (182 * ksp) >> 4;
    const int it1 = (182 * (ksp + 1)) >> 4;
    const int wave = t >> 6, lane = t & 63;
    const int mh = wave & 1, nh = wave >> 1;       // wave tile 64(d) x 80(i)
    const int l15 = lane & 15, q = lane >> 4;

    const int dl_s = t >> 2, jg_s = t & 3;
    // z2 base offsets for the two staged d rows: elem = z2[c*6400 + (hk+kh)*64 + wk + kw]
    int sb0, sb1;
    {
        int d = dbase + dl_s;
        unsigned du = (unsigned)d;
        int c = du / 40u, rr = d - c * 40;
        sb0 = c * 6400 + (rr >> 2) * 64 + (rr & 3);
        d = dbase + dl_s + 64;
        du = (unsigned)d;
        c = du / 40u; rr = d - c * 40;
        sb1 = c * 6400 + (rr >> 2) * 64 + (rr & 3);
    }

    f32x4 acc[4][5];
#pragma unroll
    for (int m = 0; m < 4; ++m)
#pragma unroll
        for (int n = 0; n < 5; ++n) acc[m][n] = (f32x4){0.f, 0.f, 0.f, 0.f};

    auto loadA = [&](int it, short8* pa) {   // 2 octs/thread from z2 fp32
        int jp0 = it * 32 + jg_s * 8;
        int off = (jp0 >> 6) * W_ + (jp0 & 63);
#pragma unroll
        for (int s = 0; s < 2; ++s) {
            int a0 = min((s ? sb1 : sb0) + off, NZ - 8);   // clamp: only pad cols affected
            f32x4 v0 = load4u(z2 + a0);
            f32x4 v1 = load4u(z2 + a0 + 4);
            unsigned short u[8];
#pragma unroll
            for (int e = 0; e < 4; ++e) { u[e] = f2bf(v0[e]); u[4 + e] = f2bf(v1[e]); }
            pa[s] = *(short8*)u;
        }
    };
    auto loadB = [&](int it, short8* pb) {   // 640 units (u = i*4 + oct) from Atn2
#pragma unroll
        for (int s = 0; s < 3; ++s) {
            int u = t + s * 256;
            if (u < 640)
                pb[s] = *(const short8*)(Atn2 + ((size_t)(it * 4 + (u & 3)) * 160 + (u >> 2)) * 8);
        }
    };
    auto writeAB = [&](int p, const short8* pa, const short8* pb) {
        *(short8*)&As[p][dl_s * 40 + jg_s * 8] = pa[0];
        *(short8*)&As[p][(dl_s + 64) * 40 + jg_s * 8] = pa[1];
#pragma unroll
        for (int s = 0; s < 3; ++s) {
            int u = t + s * 256;
            if (u < 640) *(short8*)&Bs[p][(u >> 2) * 40 + (u & 3) * 8] = pb[s];
        }
    };

    short8 pa[2], pb[3];
    loadA(it0, pa); loadB(it0, pb);
    writeAB(0, pa, pb);
    __syncthreads();

    for (int it = it0; it < it1; ++it) {
        int p = (it - it0) & 1;
        bool more = (it + 1 < it1);
        if (more) { loadA(it + 1, pa); loadB(it + 1, pb); }
        short8 af[4], bf[5];
#pragma unroll
        for (int m = 0; m < 4; ++m)
            af[m] = *(const short8*)&As[p][(mh * 64 + m * 16 + l15) * 40 + q * 8];
#pragma unroll
        for (int n = 0; n < 5; ++n)
            bf[n] = *(const short8*)&Bs[p][((nh * 5 + n) * 16 + l15) * 40 + q * 8];
#pragma unroll
        for (int m = 0; m < 4; ++m)
#pragma unroll
            for (int n = 0; n < 5; ++n)
                acc[m][n] = __builtin_amdgcn_mfma_f32_16x16x32_bf16(af[m], bf[n], acc[m][n], 0, 0, 0);
        if (more) writeAB(p ^ 1, pa, pb);
        __syncthreads();
    }
    unsigned short* base = Oph + (size_t)ksp * ((size_t)NZ);
#pragma unroll
    for (int m = 0; m < 4; ++m) {
        int d0 = dbase + mh * 64 + m * 16 + q * 4;
#pragma unroll
        for (int n = 0; n < 5; ++n) {
            int i = (nh * 5 + n) * 16 + l15;
#pragma unroll
            for (int r = 0; r < 4; ++r)
                base[(size_t)(d0 + r) * 160 + i] = f2h(acc[m][n][r]);
        }
    }
}

// ---------------------------------------------------------------------------
// reduce: out = sum of 16 fp16 partials; 8 elems/thread; grid 400 x 256.
// ---------------------------------------------------------------------------
__global__ __launch_bounds__(256) void reduce_kernel(const unsigned short* __restrict__ Oph,
                                                     float* __restrict__ out) {
    int tid = blockIdx.x * 256 + threadIdx.x;   // < 102400
    int f = tid * 8;
    float s[8];
#pragma unroll
    for (int e = 0; e < 8; ++e) s[e] = 0.f;
#pragma unroll
    for (int p = 0; p < KS2; ++p) {
        ushort8 h = *(const ushort8*)(Oph + (size_t)p * NZ + f);
#pragma unroll
        for (int e = 0; e < 8; ++e) s[e] += h2f(h[e]);
    }
    int d = f / 160, i0 = f - d * 160;          // 8-run stays within one d
    int c = d / 40, rr = d - c * 40;
    int kh = rr >> 2, kw = rr & 3;
    int obase = c * 6400 + kh * W_ + kw;
#pragma unroll
    for (int e = 0; e < 8; ++e) {
        int i = i0 + e;
        int ih = i >> 4, iw = i & 15;
        out[obase + ih * (KH_ * W_) + iw * KW_] = s[e];
    }
}

extern "C" void kernel_launch(void* const* d_in, const int* in_sizes, int n_in,
                              void* d_out, int out_size, void* d_ws, size_t ws_size,
                              hipStream_t stream) {
    const float* z1 = (const float*)d_in[0];
    const float* z2 = (const float*)d_in[1];
    float* out = (float*)d_out;

    char* w = (char*)d_ws;
    unsigned short* Qb2  = (unsigned short*)(w);                 // 1,638,400 B
    unsigned short* X    = (unsigned short*)(w + 1638400);       // 13,107,200 B
    unsigned short* Atn2 = (unsigned short*)(w + 14745600);      // 1,863,680 B
    unsigned short* Sph  = (unsigned short*)(w + 16609280);      // 29,818,880 B (16 fp16 partials)
    unsigned short* Oph  = (unsigned short*)(w + 46428160);      // 26,214,400 B (16 fp16 partials)

    pack_kernel<<<3600, 256, 0, stream>>>(z1, z2, Qb2, X);
    gemm1_kernel<<<dim3(KS1, 46), 256, 0, stream>>>(Qb2, X, Sph);
    softmax_kernel<<<160, 256, 0, stream>>>(Sph, Atn2);
    gemm2_kernel<<<dim3(KS2, 40), 256, 0, stream>>>(Atn2, z2, Oph);
    reduce_kernel<<<400, 256, 0, stream>>>(Oph, out);
}